// Round 3
// baseline (6025.283 us; speedup 1.0000x reference)
//
#include <hip/hip_runtime.h>
#include <hip/hip_bf16.h>
#include <math.h>

#define BB 32
#define SS 256
#define EE 512
#define HH 1024
#define LDM 256
#define NROW (BB*SS)   // 8192
#define NWG 64         // cooperative wgs for recurrence

typedef __attribute__((ext_vector_type(8))) short bf16x8;
typedef __attribute__((ext_vector_type(4))) float f32x4;

static __device__ inline unsigned short f2bf(float f){
  unsigned u = __float_as_uint(f);
  unsigned r = (u + 0x7fffu + ((u >> 16) & 1u)) >> 16;
  return (unsigned short)r;
}

// ---------------- sort (stable argsort by descending length) ----------------
__global__ void k_sort(const int* __restrict__ length, int* __restrict__ sorted_idx){
  int b = threadIdx.x;
  if (b >= BB) return;
  int lb = length[b];
  int r = 0;
  for (int o = 0; o < BB; ++o){
    int lo = length[o];
    if (lo > lb || (lo == lb && o < b)) ++r;
  }
  sorted_idx[r] = b;
}

// token / target maps in sorted order
__global__ void k_maps(const int* __restrict__ sorted_idx,
                       const int* __restrict__ inp_seq, const int* __restrict__ tgt_seq,
                       int* __restrict__ tokmap, int* __restrict__ tgtmap){
  int bs = blockIdx.x; int t = threadIdx.x;
  int b = sorted_idx[bs];
  tokmap[bs*SS + t] = inp_seq[b*SS + t];
  tgtmap[bs*SS + t] = tgt_seq[b*SS + t];
}

// hid = z @ l2h_w.T + l2h_b, written DIRECTLY in bf16 fragment-major layout
// hb0[layer][ (j>>3)*256 + b'*8 + (j&7) ]  matching MFMA A-frag reads.
__global__ __launch_bounds__(256) void k_hid(const float* __restrict__ z,
        const float* __restrict__ w, const float* __restrict__ bias,
        ushort* __restrict__ hb0){
  int id = blockIdx.x*256 + threadIdx.x;      // flat [B,2H] index = b*2048 + c
  int b = id >> 11, c = id & 2047;
  const float4* zr = (const float4*)(z + b*LDM);
  const float4* wr = (const float4*)(w + (size_t)c*LDM);
  float a0=0,a1=0,a2=0,a3=0;
  #pragma unroll 4
  for (int k=0;k<LDM/4;k++){ float4 zz=zr[k], ww=wr[k];
    a0+=zz.x*ww.x; a1+=zz.y*ww.y; a2+=zz.z*ww.z; a3+=zz.w*ww.w; }
  float val = a0+a1+a2+a3 + bias[c];
  // reshape(NL,B,H) of the flat [B,2H] array:
  int layer = id >> 15, bp = (id >> 10) & 31, j = id & 1023;
  hb0[(layer<<15) + ((j>>3)<<8) + (bp<<3) + (j&7)] = f2bf(val);
}

// ---------------- generic tiled fp32 GEMM: C[M,N] = A[M,K] @ Bm[N,K]^T (+bias0+bias1)
__global__ __launch_bounds__(256) void k_gemm(
    const float* __restrict__ A, int lda, const int* __restrict__ rowmap,
    const float* __restrict__ Bm,
    const float* __restrict__ bias0, const float* __restrict__ bias1,
    float* __restrict__ C, int M, int N, int K)
{
  __shared__ float As[16][64];
  __shared__ float Bs[16][64];
  int nt = blockIdx.x * 64, mt = blockIdx.y * 64;
  int t = threadIdx.x;
  int tn = t & 15, tm = t >> 4;
  int lr = t >> 2;          // 0..63
  int lk = (t & 3) * 4;     // 0,4,8,12
  float acc[4][4] = {{0.f}};
  for (int k0 = 0; k0 < K; k0 += 16){
    int ar = mt + lr;
    const float* ap = A + (size_t)(rowmap ? rowmap[ar] : ar) * lda + k0 + lk;
    float4 av = *(const float4*)ap;
    As[lk+0][lr]=av.x; As[lk+1][lr]=av.y; As[lk+2][lr]=av.z; As[lk+3][lr]=av.w;
    int bn = nt + lr;
    float4 bv = make_float4(0.f,0.f,0.f,0.f);
    if (bn < N) bv = *(const float4*)(Bm + (size_t)bn*K + k0 + lk);
    Bs[lk+0][lr]=bv.x; Bs[lk+1][lr]=bv.y; Bs[lk+2][lr]=bv.z; Bs[lk+3][lr]=bv.w;
    __syncthreads();
    #pragma unroll
    for (int k=0;k<16;k++){
      float4 a4 = *(const float4*)&As[k][tm*4];
      float4 b4 = *(const float4*)&Bs[k][tn*4];
      float a[4]={a4.x,a4.y,a4.z,a4.w}, bb[4]={b4.x,b4.y,b4.z,b4.w};
      #pragma unroll
      for (int i=0;i<4;i++)
        #pragma unroll
        for (int j=0;j<4;j++) acc[i][j] += a[i]*bb[j];
    }
    __syncthreads();
  }
  #pragma unroll
  for (int i=0;i<4;i++){
    int row = mt + tm*4 + i;
    #pragma unroll
    for (int j=0;j<4;j++){
      int col = nt + tn*4 + j;
      if (col < N){
        float v = acc[i][j];
        if (bias0) v += bias0[col];
        if (bias1) v += bias1[col];
        C[(size_t)row*N + col] = v;
      }
    }
  }
}

// ---------------- cooperative persistent RNN recurrence ----------------
// 64 wgs; wg owns cols j0..j0+15 of h (rows of Whh), bf16 in LDS frag order.
// Per step: slice GEMM via MFMA (4 waves split K), LDS reduce, tanh.
// Step tail ordering keeps HBM traffic off the barrier critical path:
//   dst(bf16,L2) -> release flag -> fp32 h + pre prefetch (overlap poll) -> poll.
__global__ __launch_bounds__(256) void k_rnn_coop(
    float* __restrict__ buf, const float* __restrict__ whh,
    const ushort* __restrict__ hb0, ushort* __restrict__ hbP,
    int* flags, int layer)
{
  __shared__ ushort whhF[16384];      // [kblk 0..127][col 0..15][8] bf16 — frag order
  __shared__ float red[4*544];        // [wv][row 0..31][17] padded (kills 4-way)
  const int wg  = blockIdx.x;
  const int tid = threadIdx.x;
  const int j0  = wg * 16;

  // load + convert Whh slice once; write in frag-major order
  for (int c = tid; c < 4096; c += 256){
    int r = c >> 8, cc = (c & 255) * 4;
    float4 w4 = *(const float4*)&whh[(size_t)(j0 + r)*HH + cc];
    uint2 p;
    p.x = (unsigned)f2bf(w4.x) | ((unsigned)f2bf(w4.y) << 16);
    p.y = (unsigned)f2bf(w4.z) | ((unsigned)f2bf(w4.w) << 16);
    *(uint2*)&whhF[((cc >> 3)*16 + r)*8 + (cc & 7)] = p;
  }
  const int lane = tid & 63, wv = tid >> 6;
  const int col = lane & 15, quad = lane >> 4;
  const int ob0 = tid >> 4, oj = tid & 15;
  const ushort* src0 = hb0 + (layer << 15);

  // prefetch step-0 pre-activations
  float pre0 = buf[((size_t)ob0*SS + 0)*HH + j0 + oj];
  float pre1 = buf[((size_t)(ob0+16)*SS + 0)*HH + j0 + oj];
  __syncthreads();

  for (int t = 0; t < SS; ++t){
    const ushort* src = (t == 0) ? src0 : hbP + (1 - (t & 1)) * 32768;
    ushort* dst = hbP + (t & 1) * 32768;

    f32x4 acc0 = {0.f,0.f,0.f,0.f}, acc1 = {0.f,0.f,0.f,0.f};
    #pragma unroll
    for (int ks = 0; ks < 8; ++ks){
      int kb = wv*32 + ks*4 + quad;                              // k-block (8 elems)
      bf16x8 bfr = *(const bf16x8*)&whhF[(kb*16 + col)*8];       // contiguous 1KB/wave
      bf16x8 a0 = *(const bf16x8*)&src[(kb << 8) + (col << 3)];
      bf16x8 a1 = *(const bf16x8*)&src[(kb << 8) + ((col + 16) << 3)];
      acc0 = __builtin_amdgcn_mfma_f32_16x16x32_bf16(a0, bfr, acc0, 0, 0, 0);
      acc1 = __builtin_amdgcn_mfma_f32_16x16x32_bf16(a1, bfr, acc1, 0, 0, 0);
    }
    // partials to LDS: red[wv][row=b][col=j], padded stride 17
    #pragma unroll
    for (int r = 0; r < 4; ++r){
      red[wv*544 + (quad*4 + r)*17 + col]        = acc0[r];
      red[wv*544 + (16 + quad*4 + r)*17 + col]   = acc1[r];
    }
    __syncthreads();

    // reduce 4 waves, tanh; write bf16 dst FIRST (only thing the flag waits on)
    float vv[2];
    #pragma unroll
    for (int i = 0; i < 2; ++i){
      int o = tid + i*256;
      int b = o >> 4, j = o & 15;
      int ro = b*17 + j;
      float s = red[ro] + red[544 + ro] + red[1088 + ro] + red[1632 + ro];
      vv[i] = tanhf((i ? pre1 : pre0) + s);
      int k = j0 + j;
      dst[((k >> 3) << 8) + (b << 3) + (k & 7)] = f2bf(vv[i]);
    }
    // release: drains only the 512B dst store (L2), not HBM traffic
    if (tid == 0)
      __hip_atomic_store(&flags[wg], t + 1, __ATOMIC_RELEASE, __HIP_MEMORY_SCOPE_AGENT);

    // off-critical-path: fp32 h to HBM + next-step pre prefetch (overlap poll)
    #pragma unroll
    for (int i = 0; i < 2; ++i){
      int o = tid + i*256;
      int b = o >> 4, j = o & 15;
      buf[((size_t)b*SS + t)*HH + j0 + j] = vv[i];
    }
    int tn2 = (t + 1 < SS) ? t + 1 : t;
    pre0 = buf[((size_t)ob0*SS + tn2)*HH + j0 + oj];
    pre1 = buf[((size_t)(ob0+16)*SS + tn2)*HH + j0 + oj];

    if (tid < NWG){
      while (__hip_atomic_load(&flags[tid], __ATOMIC_RELAXED, __HIP_MEMORY_SCOPE_AGENT) < t + 1)
        __builtin_amdgcn_s_sleep(1);
    }
    __syncthreads();
    __threadfence();   // acquire: invalidate stale caches before reading peers' h
  }
}

// ---------------- fused cluster logsumexp ----------------
__global__ __launch_bounds__(256) void k_cluster(
    const float* __restrict__ proj, int Kp,
    const float* __restrict__ W, int Nc,
    float* __restrict__ stats, int ci)
{
  __shared__ float ps[4][4][256];
  int lane = threadIdx.x & 63;
  int wvl  = threadIdx.x >> 6;           // wave in block 0..3
  int r0 = (blockIdx.x*4 + wvl) * 4;     // first of this wave's 4 rows
  for (int r=0;r<4;r++)
    for (int k=lane;k<Kp;k+=64)
      ps[wvl][r][k] = proj[(size_t)(r0+r)*Kp + k];
  __syncthreads();
  float mx[4], sm[4];
  #pragma unroll
  for (int r=0;r<4;r++){ mx[r]=-1e30f; sm[r]=0.f; }
  for (int n=lane; n<Nc; n+=64){
    const float* wr = W + (size_t)n*Kp;
    float l[4]={0.f,0.f,0.f,0.f};
    for (int k=0;k<Kp;k+=4){
      float4 w4 = *(const float4*)(wr+k);
      #pragma unroll
      for (int r=0;r<4;r++){
        l[r] += w4.x*ps[wvl][r][k] + w4.y*ps[wvl][r][k+1]
              + w4.z*ps[wvl][r][k+2] + w4.w*ps[wvl][r][k+3];
      }
    }
    #pragma unroll
    for (int r=0;r<4;r++){
      float nm = fmaxf(mx[r], l[r]);
      sm[r] = sm[r]*__expf(mx[r]-nm) + __expf(l[r]-nm);
      mx[r] = nm;
    }
  }
  #pragma unroll
  for (int r=0;r<4;r++){
    for (int off=32; off; off>>=1){
      float om = __shfl_down(mx[r], off);
      float os = __shfl_down(sm[r], off);
      float nm = fmaxf(mx[r], om);
      sm[r] = sm[r]*__expf(mx[r]-nm) + os*__expf(om-nm);
      mx[r] = nm;
    }
    if (lane==0){
      stats[(size_t)(r0+r)*6 + ci*2 + 0] = mx[r];
      stats[(size_t)(r0+r)*6 + ci*2 + 1] = sm[r];
    }
  }
}

// ---------------- target logit for tail clusters (one wave per row) ----------------
__global__ __launch_bounds__(256) void k_tlogit(
    const int* __restrict__ tgtmap,
    const float* __restrict__ proj0, const float* __restrict__ proj1, const float* __restrict__ proj2,
    const float* __restrict__ w0, const float* __restrict__ w1, const float* __restrict__ w2,
    float* __restrict__ tlogit)
{
  int lane = threadIdx.x & 63;
  int row = (blockIdx.x * 256 + threadIdx.x) >> 6;
  int tgt = tgtmap[row];
  float acc = 0.f;
  const float* pr = nullptr; const float* wr = nullptr; int Kp = 0;
  if      (tgt >= 1000){ pr = proj2 + (size_t)row*16;  wr = w2 + (size_t)(tgt-1000)*16;  Kp=16;  }
  else if (tgt >= 100) { pr = proj1 + (size_t)row*64;  wr = w1 + (size_t)(tgt-100)*64;   Kp=64;  }
  else if (tgt >= 30)  { pr = proj0 + (size_t)row*256; wr = w0 + (size_t)(tgt-30)*256;   Kp=256; }
  for (int k=lane; k<Kp; k+=64) acc += pr[k]*wr[k];
  for (int off=32; off; off>>=1) acc += __shfl_down(acc, off);
  if (lane==0) tlogit[row] = acc;
}

// ---------------- final: head LSE + assemble NLL, reduce ----------------
__global__ __launch_bounds__(256) void k_final(
    const float* __restrict__ head, const float* __restrict__ stats,
    const float* __restrict__ tlogit, const int* __restrict__ tgtmap,
    float* __restrict__ out)
{
  int row = blockIdx.x*256 + threadIdx.x;
  int tgt = tgtmap[row];
  float nll = 0.f;
  if (tgt != 0){
    const float* hrow = head + (size_t)row*33;
    float m = hrow[0];
    #pragma unroll
    for (int i=1;i<33;i++) m = fmaxf(m, hrow[i]);
    float s = 0.f;
    #pragma unroll
    for (int i=0;i<33;i++) s += __expf(hrow[i]-m);
    float lse = __logf(s) + m;
    int ci = (tgt>=1000) ? 2 : (tgt>=100) ? 1 : (tgt>=30) ? 0 : -1;
    if (ci < 0){
      nll = lse - hrow[tgt];
    } else {
      float cm = stats[(size_t)row*6 + ci*2 + 0];
      float cs = stats[(size_t)row*6 + ci*2 + 1];
      nll = lse - hrow[30+ci] + (__logf(cs) + cm - tlogit[row]);
    }
  }
  float v = nll;
  for (int off=32; off; off>>=1) v += __shfl_down(v, off);
  __shared__ float wsum[4];
  int lane = threadIdx.x & 63, wv = threadIdx.x >> 6;
  if (lane==0) wsum[wv] = v;
  __syncthreads();
  if (threadIdx.x==0) atomicAdd(out, wsum[0]+wsum[1]+wsum[2]+wsum[3]);
}

extern "C" void kernel_launch(void* const* d_in, const int* in_sizes, int n_in,
                              void* d_out, int out_size, void* d_ws, size_t ws_size,
                              hipStream_t stream)
{
  const float* z      = (const float*)d_in[0];
  const float* emb    = (const float*)d_in[1];
  const float* l2h_w  = (const float*)d_in[2];
  const float* l2h_b  = (const float*)d_in[3];
  const float* w0ih   = (const float*)d_in[4];
  const float* w0hh   = (const float*)d_in[5];
  const float* b0ih   = (const float*)d_in[6];
  const float* b0hh   = (const float*)d_in[7];
  const float* w1ih   = (const float*)d_in[8];
  const float* w1hh   = (const float*)d_in[9];
  const float* b1ih   = (const float*)d_in[10];
  const float* b1hh   = (const float*)d_in[11];
  const float* head_w = (const float*)d_in[12];
  const float* p0     = (const float*)d_in[13];
  const float* tw0    = (const float*)d_in[14];
  const float* p1     = (const float*)d_in[15];
  const float* tw1    = (const float*)d_in[16];
  const float* p2     = (const float*)d_in[17];
  const float* tw2    = (const float*)d_in[18];
  const int* inp_seq  = (const int*)d_in[19];
  const int* tgt_seq  = (const int*)d_in[20];
  const int* length   = (const int*)d_in[21];

  float* ws   = (float*)d_ws;
  ushort* hb0 = (ushort*)ws;                      // 65536 ushorts
  ushort* hbP = hb0 + 65536;                      // 65536 ushorts
  float* bufA = ws + 65536;                       // 8192*1024  (pre0 -> h1; later head/proj/stats)
  float* bufB = bufA + (size_t)NROW*HH;           // 8192*1024  (pre1 -> h2)
  int*   ibuf = (int*)(bufB + (size_t)NROW*HH);
  int* sorted_idx = ibuf;                         // 32
  int* tokmap = ibuf + 32;                        // 8192
  int* tgtmap = tokmap + NROW;                    // 8192
  int* flags  = tgtmap + NROW;                    // 128 (2 layers x 64)
  // aliased into bufA once h1 is consumed (after pre1 GEMM):
  float* headL = bufA;                            // 8192*33
  float* proj0 = headL + (size_t)NROW*33;         // 8192*256
  float* proj1 = proj0 + (size_t)NROW*256;        // 8192*64
  float* proj2 = proj1 + (size_t)NROW*64;         // 8192*16
  float* stats = proj2 + (size_t)NROW*16;         // 8192*6
  float* tlog  = stats + (size_t)NROW*6;          // 8192

  float* outF = (float*)d_out;
  hipMemsetAsync(outF, 0, sizeof(float), stream);
  hipMemsetAsync(flags, 0, 128*sizeof(int), stream);

  k_sort<<<1, 32, 0, stream>>>(length, sorted_idx);
  k_maps<<<32, 256, 0, stream>>>(sorted_idx, inp_seq, tgt_seq, tokmap, tgtmap);
  k_hid<<<256, 256, 0, stream>>>(z, l2h_w, l2h_b, hb0);

  // pre0 = emb[tok] @ w0ih^T + b0ih + b0hh
  k_gemm<<<dim3(HH/64, NROW/64), 256, 0, stream>>>(emb, EE, tokmap, w0ih, b0ih, b0hh,
                                                   bufA, NROW, HH, EE);
  k_rnn_coop<<<NWG, 256, 0, stream>>>(bufA, w0hh, hb0, hbP, flags, 0);      // bufA := h1
  // pre1 = h1 @ w1ih^T + b1ih + b1hh
  k_gemm<<<dim3(HH/64, NROW/64), 256, 0, stream>>>(bufA, HH, nullptr, w1ih, b1ih, b1hh,
                                                   bufB, NROW, HH, HH);
  k_rnn_coop<<<NWG, 256, 0, stream>>>(bufB, w1hh, hb0, hbP, flags + 64, 1); // bufB := h2

  // head logits + tail projections
  k_gemm<<<dim3(1, NROW/64), 256, 0, stream>>>(bufB, HH, nullptr, head_w, nullptr, nullptr,
                                               headL, NROW, 33, HH);
  k_gemm<<<dim3(4, NROW/64), 256, 0, stream>>>(bufB, HH, nullptr, p0, nullptr, nullptr,
                                               proj0, NROW, 256, HH);
  k_gemm<<<dim3(1, NROW/64), 256, 0, stream>>>(bufB, HH, nullptr, p1, nullptr, nullptr,
                                               proj1, NROW, 64, HH);
  k_gemm<<<dim3(1, NROW/64), 256, 0, stream>>>(bufB, HH, nullptr, p2, nullptr, nullptr,
                                               proj2, NROW, 16, HH);

  k_cluster<<<NROW/16, 256, 0, stream>>>(proj0, 256, tw0, 70,    stats, 0);
  k_cluster<<<NROW/16, 256, 0, stream>>>(proj1, 64,  tw1, 900,   stats, 1);
  k_cluster<<<NROW/16, 256, 0, stream>>>(proj2, 16,  tw2, 19000, stats, 2);
  k_tlogit<<<NROW/4, 256, 0, stream>>>(tgtmap, proj0, proj1, proj2, tw0, tw1, tw2, tlog);
  k_final<<<NROW/256, 256, 0, stream>>>(headL, stats, tlog, tgtmap, outF);
}

// Round 4
// 3310.169 us; speedup vs baseline: 1.8202x; 1.8202x over previous
//
#include <hip/hip_runtime.h>
#include <hip/hip_bf16.h>
#include <math.h>

#define BB 32
#define SS 256
#define EE 512
#define HH 1024
#define LDM 256
#define NROW (BB*SS)   // 8192
#define NWG 64         // cooperative wgs for recurrence

typedef __attribute__((ext_vector_type(8))) short bf16x8;
typedef __attribute__((ext_vector_type(4))) float f32x4;

static __device__ inline unsigned short f2bf(float f){
  unsigned u = __float_as_uint(f);
  unsigned r = (u + 0x7fffu + ((u >> 16) & 1u)) >> 16;
  return (unsigned short)r;
}

// fast tanh: 1 - 2/(e^{2x}+1). |x| large saturates correctly via __expf inf/0.
static __device__ inline float ftanh(float x){
  float e = __expf(2.f*x);
  return 1.f - 2.f/(e + 1.f);
}

// LLC-direct (agent-coherent) 16B fragment load as 2x8B relaxed atomics.
static __device__ inline bf16x8 ld_frag(const unsigned long long* p){
  union { unsigned long long u[2]; bf16x8 v; } t;
  t.u[0] = __hip_atomic_load((unsigned long long*)p,     __ATOMIC_RELAXED, __HIP_MEMORY_SCOPE_AGENT);
  t.u[1] = __hip_atomic_load((unsigned long long*)p + 1, __ATOMIC_RELAXED, __HIP_MEMORY_SCOPE_AGENT);
  return t.v;
}

// ---------------- sort (stable argsort by descending length) ----------------
__global__ void k_sort(const int* __restrict__ length, int* __restrict__ sorted_idx){
  int b = threadIdx.x;
  if (b >= BB) return;
  int lb = length[b];
  int r = 0;
  for (int o = 0; o < BB; ++o){
    int lo = length[o];
    if (lo > lb || (lo == lb && o < b)) ++r;
  }
  sorted_idx[r] = b;
}

// token / target maps in sorted order
__global__ void k_maps(const int* __restrict__ sorted_idx,
                       const int* __restrict__ inp_seq, const int* __restrict__ tgt_seq,
                       int* __restrict__ tokmap, int* __restrict__ tgtmap){
  int bs = blockIdx.x; int t = threadIdx.x;
  int b = sorted_idx[bs];
  tokmap[bs*SS + t] = inp_seq[b*SS + t];
  tgtmap[bs*SS + t] = tgt_seq[b*SS + t];
}

// hid = z @ l2h_w.T + l2h_b, written DIRECTLY in bf16 fragment-major layout
// hb0[layer][ (j>>3)*256 + b'*8 + (j&7) ]  matching MFMA A-frag reads.
__global__ __launch_bounds__(256) void k_hid(const float* __restrict__ z,
        const float* __restrict__ w, const float* __restrict__ bias,
        ushort* __restrict__ hb0){
  int id = blockIdx.x*256 + threadIdx.x;      // flat [B,2H] index = b*2048 + c
  int b = id >> 11, c = id & 2047;
  const float4* zr = (const float4*)(z + b*LDM);
  const float4* wr = (const float4*)(w + (size_t)c*LDM);
  float a0=0,a1=0,a2=0,a3=0;
  #pragma unroll 4
  for (int k=0;k<LDM/4;k++){ float4 zz=zr[k], ww=wr[k];
    a0+=zz.x*ww.x; a1+=zz.y*ww.y; a2+=zz.z*ww.z; a3+=zz.w*ww.w; }
  float val = a0+a1+a2+a3 + bias[c];
  // reshape(NL,B,H) of the flat [B,2H] array:
  int layer = id >> 15, bp = (id >> 10) & 31, j = id & 1023;
  hb0[(layer<<15) + ((j>>3)<<8) + (bp<<3) + (j&7)] = f2bf(val);
}

// ---------------- generic tiled fp32 GEMM: C[M,N] = A[M,K] @ Bm[N,K]^T (+bias0+bias1)
__global__ __launch_bounds__(256) void k_gemm(
    const float* __restrict__ A, int lda, const int* __restrict__ rowmap,
    const float* __restrict__ Bm,
    const float* __restrict__ bias0, const float* __restrict__ bias1,
    float* __restrict__ C, int M, int N, int K)
{
  __shared__ float As[16][64];
  __shared__ float Bs[16][64];
  int nt = blockIdx.x * 64, mt = blockIdx.y * 64;
  int t = threadIdx.x;
  int tn = t & 15, tm = t >> 4;
  int lr = t >> 2;          // 0..63
  int lk = (t & 3) * 4;     // 0,4,8,12
  float acc[4][4] = {{0.f}};
  for (int k0 = 0; k0 < K; k0 += 16){
    int ar = mt + lr;
    const float* ap = A + (size_t)(rowmap ? rowmap[ar] : ar) * lda + k0 + lk;
    float4 av = *(const float4*)ap;
    As[lk+0][lr]=av.x; As[lk+1][lr]=av.y; As[lk+2][lr]=av.z; As[lk+3][lr]=av.w;
    int bn = nt + lr;
    float4 bv = make_float4(0.f,0.f,0.f,0.f);
    if (bn < N) bv = *(const float4*)(Bm + (size_t)bn*K + k0 + lk);
    Bs[lk+0][lr]=bv.x; Bs[lk+1][lr]=bv.y; Bs[lk+2][lr]=bv.z; Bs[lk+3][lr]=bv.w;
    __syncthreads();
    #pragma unroll
    for (int k=0;k<16;k++){
      float4 a4 = *(const float4*)&As[k][tm*4];
      float4 b4 = *(const float4*)&Bs[k][tn*4];
      float a[4]={a4.x,a4.y,a4.z,a4.w}, bb[4]={b4.x,b4.y,b4.z,b4.w};
      #pragma unroll
      for (int i=0;i<4;i++)
        #pragma unroll
        for (int j=0;j<4;j++) acc[i][j] += a[i]*bb[j];
    }
    __syncthreads();
  }
  #pragma unroll
  for (int i=0;i<4;i++){
    int row = mt + tm*4 + i;
    #pragma unroll
    for (int j=0;j<4;j++){
      int col = nt + tn*4 + j;
      if (col < N){
        float v = acc[i][j];
        if (bias0) v += bias0[col];
        if (bias1) v += bias1[col];
        C[(size_t)row*N + col] = v;
      }
    }
  }
}

// ---------------- cooperative persistent RNN recurrence ----------------
// 64 wgs; wg owns cols j0..j0+15 of h, Whh slice bf16 in LDS (frag order).
// ALL cross-wg data (h exchange + flags) moves via RELAXED+AGENT atomics
// (write-through to LLC / LLC-direct loads) -> NO buffer_wbl2 / buffer_inv
// in the step loop (those full-L2 maintenance ops were the r2/r3 bottleneck).
__global__ __launch_bounds__(256) void k_rnn_coop(
    float* __restrict__ buf, const float* __restrict__ whh,
    const ushort* __restrict__ hb0, ushort* __restrict__ hbP,
    int* flags, int layer)
{
  __shared__ ushort whhF[16384];      // [kblk 0..127][col 0..15][8] bf16 — frag order
  __shared__ float red[4*544];        // [wv][row 0..31][17] padded
  const int wg  = blockIdx.x;
  const int tid = threadIdx.x;
  const int j0  = wg * 16;

  // load + convert Whh slice once; write in frag-major order
  for (int c = tid; c < 4096; c += 256){
    int r = c >> 8, cc = (c & 255) * 4;
    float4 w4 = *(const float4*)&whh[(size_t)(j0 + r)*HH + cc];
    uint2 p;
    p.x = (unsigned)f2bf(w4.x) | ((unsigned)f2bf(w4.y) << 16);
    p.y = (unsigned)f2bf(w4.z) | ((unsigned)f2bf(w4.w) << 16);
    *(uint2*)&whhF[((cc >> 3)*16 + r)*8 + (cc & 7)] = p;
  }
  const int lane = tid & 63, wv = tid >> 6;
  const int col = lane & 15, quad = lane >> 4;
  // output pair owned by this thread: rows o=2*tid, 2*tid+1  (b = tid>>3, j = (2*tid)&15)
  const int ob = tid >> 3, oj = (tid << 1) & 15;
  const ushort* src0 = hb0 + (layer << 15);

  // prefetch step-0 pre-activations (float2: j even, 8B aligned)
  float2 pre = *(const float2*)&buf[((size_t)ob*SS + 0)*HH + j0 + oj];
  __syncthreads();

  for (int t = 0; t < SS; ++t){
    const ushort* src = (t == 0) ? src0 : hbP + (1 - (t & 1)) * 32768;
    ushort* dst = hbP + (t & 1) * 32768;
    const unsigned long long* s64 = (const unsigned long long*)src;

    // batch-issue all 32 LLC-direct frag loads (one latency), then MFMA
    bf16x8 a0f[8], a1f[8];
    #pragma unroll
    for (int ks = 0; ks < 8; ++ks){
      int kb = wv*32 + ks*4 + quad;
      const unsigned long long* p = s64 + (kb << 6) + (col << 1);
      a0f[ks] = ld_frag(p);
      a1f[ks] = ld_frag(p + 32);
    }
    f32x4 acc0 = {0.f,0.f,0.f,0.f}, acc1 = {0.f,0.f,0.f,0.f};
    #pragma unroll
    for (int ks = 0; ks < 8; ++ks){
      int kb = wv*32 + ks*4 + quad;
      bf16x8 bfr = *(const bf16x8*)&whhF[(kb*16 + col)*8];   // contiguous 1KB/wave
      acc0 = __builtin_amdgcn_mfma_f32_16x16x32_bf16(a0f[ks], bfr, acc0, 0, 0, 0);
      acc1 = __builtin_amdgcn_mfma_f32_16x16x32_bf16(a1f[ks], bfr, acc1, 0, 0, 0);
    }
    // partials to LDS: red[wv][row=b][col=j], padded stride 17
    #pragma unroll
    for (int r = 0; r < 4; ++r){
      red[wv*544 + (quad*4 + r)*17 + col]        = acc0[r];
      red[wv*544 + (16 + quad*4 + r)*17 + col]   = acc1[r];
    }
    __syncthreads();

    // reduce 4 waves, tanh, pack 2 bf16 -> one LLC-direct uint store
    int ro = ob*17 + oj;
    float s0 = red[ro]   + red[544 + ro]   + red[1088 + ro]   + red[1632 + ro];
    float s1 = red[ro+1] + red[544 + ro+1] + red[1088 + ro+1] + red[1632 + ro+1];
    float v0 = ftanh(pre.x + s0);
    float v1 = ftanh(pre.y + s1);
    int k = j0 + oj;
    unsigned pk = (unsigned)f2bf(v0) | ((unsigned)f2bf(v1) << 16);
    __hip_atomic_store((unsigned*)dst + ((k >> 3) << 7) + (ob << 2) + ((k & 7) >> 1),
                       pk, __ATOMIC_RELAXED, __HIP_MEMORY_SCOPE_AGENT);

    // all waves: stores acked at coherence point, then one flag per wg
    asm volatile("s_waitcnt vmcnt(0)" ::: "memory");
    __syncthreads();
    if (tid == 0)
      __hip_atomic_store(&flags[wg], t + 1, __ATOMIC_RELAXED, __HIP_MEMORY_SCOPE_AGENT);

    // off-protocol (cached path): fp32 h for later GEMMs + next pre prefetch
    *(float2*)&buf[((size_t)ob*SS + t)*HH + j0 + oj] = make_float2(v0, v1);
    int tn2 = (t + 1 < SS) ? t + 1 : t;
    pre = *(const float2*)&buf[((size_t)ob*SS + tn2)*HH + j0 + oj];

    if (tid < NWG){
      while (__hip_atomic_load(&flags[tid], __ATOMIC_RELAXED, __HIP_MEMORY_SCOPE_AGENT) < t + 1)
        __builtin_amdgcn_s_sleep(1);
    }
    asm volatile("" ::: "memory");
    __syncthreads();
  }
}

// ---------------- fused cluster logsumexp ----------------
__global__ __launch_bounds__(256) void k_cluster(
    const float* __restrict__ proj, int Kp,
    const float* __restrict__ W, int Nc,
    float* __restrict__ stats, int ci)
{
  __shared__ float ps[4][4][256];
  int lane = threadIdx.x & 63;
  int wvl  = threadIdx.x >> 6;           // wave in block 0..3
  int r0 = (blockIdx.x*4 + wvl) * 4;     // first of this wave's 4 rows
  for (int r=0;r<4;r++)
    for (int k=lane;k<Kp;k+=64)
      ps[wvl][r][k] = proj[(size_t)(r0+r)*Kp + k];
  __syncthreads();
  float mx[4], sm[4];
  #pragma unroll
  for (int r=0;r<4;r++){ mx[r]=-1e30f; sm[r]=0.f; }
  for (int n=lane; n<Nc; n+=64){
    const float* wr = W + (size_t)n*Kp;
    float l[4]={0.f,0.f,0.f,0.f};
    for (int k=0;k<Kp;k+=4){
      float4 w4 = *(const float4*)(wr+k);
      #pragma unroll
      for (int r=0;r<4;r++){
        l[r] += w4.x*ps[wvl][r][k] + w4.y*ps[wvl][r][k+1]
              + w4.z*ps[wvl][r][k+2] + w4.w*ps[wvl][r][k+3];
      }
    }
    #pragma unroll
    for (int r=0;r<4;r++){
      float nm = fmaxf(mx[r], l[r]);
      sm[r] = sm[r]*__expf(mx[r]-nm) + __expf(l[r]-nm);
      mx[r] = nm;
    }
  }
  #pragma unroll
  for (int r=0;r<4;r++){
    for (int off=32; off; off>>=1){
      float om = __shfl_down(mx[r], off);
      float os = __shfl_down(sm[r], off);
      float nm = fmaxf(mx[r], om);
      sm[r] = sm[r]*__expf(mx[r]-nm) + os*__expf(om-nm);
      mx[r] = nm;
    }
    if (lane==0){
      stats[(size_t)(r0+r)*6 + ci*2 + 0] = mx[r];
      stats[(size_t)(r0+r)*6 + ci*2 + 1] = sm[r];
    }
  }
}

// ---------------- target logit for tail clusters (one wave per row) ----------------
__global__ __launch_bounds__(256) void k_tlogit(
    const int* __restrict__ tgtmap,
    const float* __restrict__ proj0, const float* __restrict__ proj1, const float* __restrict__ proj2,
    const float* __restrict__ w0, const float* __restrict__ w1, const float* __restrict__ w2,
    float* __restrict__ tlogit)
{
  int lane = threadIdx.x & 63;
  int row = (blockIdx.x * 256 + threadIdx.x) >> 6;
  int tgt = tgtmap[row];
  float acc = 0.f;
  const float* pr = nullptr; const float* wr = nullptr; int Kp = 0;
  if      (tgt >= 1000){ pr = proj2 + (size_t)row*16;  wr = w2 + (size_t)(tgt-1000)*16;  Kp=16;  }
  else if (tgt >= 100) { pr = proj1 + (size_t)row*64;  wr = w1 + (size_t)(tgt-100)*64;   Kp=64;  }
  else if (tgt >= 30)  { pr = proj0 + (size_t)row*256; wr = w0 + (size_t)(tgt-30)*256;   Kp=256; }
  for (int k=lane; k<Kp; k+=64) acc += pr[k]*wr[k];
  for (int off=32; off; off>>=1) acc += __shfl_down(acc, off);
  if (lane==0) tlogit[row] = acc;
}

// ---------------- final: head LSE + assemble NLL, reduce ----------------
__global__ __launch_bounds__(256) void k_final(
    const float* __restrict__ head, const float* __restrict__ stats,
    const float* __restrict__ tlogit, const int* __restrict__ tgtmap,
    float* __restrict__ out)
{
  int row = blockIdx.x*256 + threadIdx.x;
  int tgt = tgtmap[row];
  float nll = 0.f;
  if (tgt != 0){
    const float* hrow = head + (size_t)row*33;
    float m = hrow[0];
    #pragma unroll
    for (int i=1;i<33;i++) m = fmaxf(m, hrow[i]);
    float s = 0.f;
    #pragma unroll
    for (int i=0;i<33;i++) s += __expf(hrow[i]-m);
    float lse = __logf(s) + m;
    int ci = (tgt>=1000) ? 2 : (tgt>=100) ? 1 : (tgt>=30) ? 0 : -1;
    if (ci < 0){
      nll = lse - hrow[tgt];
    } else {
      float cm = stats[(size_t)row*6 + ci*2 + 0];
      float cs = stats[(size_t)row*6 + ci*2 + 1];
      nll = lse - hrow[30+ci] + (__logf(cs) + cm - tlogit[row]);
    }
  }
  float v = nll;
  for (int off=32; off; off>>=1) v += __shfl_down(v, off);
  __shared__ float wsum[4];
  int lane = threadIdx.x & 63, wv = threadIdx.x >> 6;
  if (lane==0) wsum[wv] = v;
  __syncthreads();
  if (threadIdx.x==0) atomicAdd(out, wsum[0]+wsum[1]+wsum[2]+wsum[3]);
}

extern "C" void kernel_launch(void* const* d_in, const int* in_sizes, int n_in,
                              void* d_out, int out_size, void* d_ws, size_t ws_size,
                              hipStream_t stream)
{
  const float* z      = (const float*)d_in[0];
  const float* emb    = (const float*)d_in[1];
  const float* l2h_w  = (const float*)d_in[2];
  const float* l2h_b  = (const float*)d_in[3];
  const float* w0ih   = (const float*)d_in[4];
  const float* w0hh   = (const float*)d_in[5];
  const float* b0ih   = (const float*)d_in[6];
  const float* b0hh   = (const float*)d_in[7];
  const float* w1ih   = (const float*)d_in[8];
  const float* w1hh   = (const float*)d_in[9];
  const float* b1ih   = (const float*)d_in[10];
  const float* b1hh   = (const float*)d_in[11];
  const float* head_w = (const float*)d_in[12];
  const float* p0     = (const float*)d_in[13];
  const float* tw0    = (const float*)d_in[14];
  const float* p1     = (const float*)d_in[15];
  const float* tw1    = (const float*)d_in[16];
  const float* p2     = (const float*)d_in[17];
  const float* tw2    = (const float*)d_in[18];
  const int* inp_seq  = (const int*)d_in[19];
  const int* tgt_seq  = (const int*)d_in[20];
  const int* length   = (const int*)d_in[21];

  float* ws   = (float*)d_ws;
  ushort* hb0 = (ushort*)ws;                      // 65536 ushorts
  ushort* hbP = hb0 + 65536;                      // 65536 ushorts
  float* bufA = ws + 65536;                       // 8192*1024  (pre0 -> h1; later head/proj/stats)
  float* bufB = bufA + (size_t)NROW*HH;           // 8192*1024  (pre1 -> h2)
  int*   ibuf = (int*)(bufB + (size_t)NROW*HH);
  int* sorted_idx = ibuf;                         // 32
  int* tokmap = ibuf + 32;                        // 8192
  int* tgtmap = tokmap + NROW;                    // 8192
  int* flags  = tgtmap + NROW;                    // 128 (2 layers x 64)
  // aliased into bufA once h1 is consumed (after pre1 GEMM):
  float* headL = bufA;                            // 8192*33
  float* proj0 = headL + (size_t)NROW*33;         // 8192*256
  float* proj1 = proj0 + (size_t)NROW*256;        // 8192*64
  float* proj2 = proj1 + (size_t)NROW*64;         // 8192*16
  float* stats = proj2 + (size_t)NROW*16;         // 8192*6
  float* tlog  = stats + (size_t)NROW*6;          // 8192

  float* outF = (float*)d_out;
  hipMemsetAsync(outF, 0, sizeof(float), stream);
  hipMemsetAsync(flags, 0, 128*sizeof(int), stream);

  k_sort<<<1, 32, 0, stream>>>(length, sorted_idx);
  k_maps<<<32, 256, 0, stream>>>(sorted_idx, inp_seq, tgt_seq, tokmap, tgtmap);
  k_hid<<<256, 256, 0, stream>>>(z, l2h_w, l2h_b, hb0);

  // pre0 = emb[tok] @ w0ih^T + b0ih + b0hh
  k_gemm<<<dim3(HH/64, NROW/64), 256, 0, stream>>>(emb, EE, tokmap, w0ih, b0ih, b0hh,
                                                   bufA, NROW, HH, EE);
  k_rnn_coop<<<NWG, 256, 0, stream>>>(bufA, w0hh, hb0, hbP, flags, 0);      // bufA := h1
  // pre1 = h1 @ w1ih^T + b1ih + b1hh
  k_gemm<<<dim3(HH/64, NROW/64), 256, 0, stream>>>(bufA, HH, nullptr, w1ih, b1ih, b1hh,
                                                   bufB, NROW, HH, HH);
  k_rnn_coop<<<NWG, 256, 0, stream>>>(bufB, w1hh, hb0, hbP, flags + 64, 1); // bufB := h2

  // head logits + tail projections
  k_gemm<<<dim3(1, NROW/64), 256, 0, stream>>>(bufB, HH, nullptr, head_w, nullptr, nullptr,
                                               headL, NROW, 33, HH);
  k_gemm<<<dim3(4, NROW/64), 256, 0, stream>>>(bufB, HH, nullptr, p0, nullptr, nullptr,
                                               proj0, NROW, 256, HH);
  k_gemm<<<dim3(1, NROW/64), 256, 0, stream>>>(bufB, HH, nullptr, p1, nullptr, nullptr,
                                               proj1, NROW, 64, HH);
  k_gemm<<<dim3(1, NROW/64), 256, 0, stream>>>(bufB, HH, nullptr, p2, nullptr, nullptr,
                                               proj2, NROW, 16, HH);

  k_cluster<<<NROW/16, 256, 0, stream>>>(proj0, 256, tw0, 70,    stats, 0);
  k_cluster<<<NROW/16, 256, 0, stream>>>(proj1, 64,  tw1, 900,   stats, 1);
  k_cluster<<<NROW/16, 256, 0, stream>>>(proj2, 16,  tw2, 19000, stats, 2);
  k_tlogit<<<NROW/4, 256, 0, stream>>>(tgtmap, proj0, proj1, proj2, tw0, tw1, tw2, tlog);
  k_final<<<NROW/256, 256, 0, stream>>>(headL, stats, tlog, tgtmap, outF);
}

// Round 5
// 2629.017 us; speedup vs baseline: 2.2918x; 1.2591x over previous
//
#include <hip/hip_runtime.h>
#include <hip/hip_bf16.h>
#include <math.h>

#define BB 32
#define SS 256
#define EE 512
#define HH 1024
#define LDM 256
#define NROW (BB*SS)   // 8192
#define NWG 64         // cooperative wgs for recurrence

typedef __attribute__((ext_vector_type(8))) short bf16x8;
typedef __attribute__((ext_vector_type(4))) float f32x4;

static __device__ inline unsigned short f2bf(float f){
  unsigned u = __float_as_uint(f);
  unsigned r = (u + 0x7fffu + ((u >> 16) & 1u)) >> 16;
  return (unsigned short)r;
}
// cheap round (no tie-to-even) for GEMM staging
static __device__ inline unsigned short f2bf_fast(float f){
  return (unsigned short)((__float_as_uint(f) + 0x8000u) >> 16);
}
static __device__ inline bf16x8 cvt8(float4 x, float4 y){
  union { ushort s[8]; bf16x8 v; } t;
  t.s[0]=f2bf_fast(x.x); t.s[1]=f2bf_fast(x.y); t.s[2]=f2bf_fast(x.z); t.s[3]=f2bf_fast(x.w);
  t.s[4]=f2bf_fast(y.x); t.s[5]=f2bf_fast(y.y); t.s[6]=f2bf_fast(y.z); t.s[7]=f2bf_fast(y.w);
  return t.v;
}

// fast tanh: 1 - 2/(e^{2x}+1)
static __device__ inline float ftanh(float x){
  float e = __expf(2.f*x);
  return 1.f - 2.f/(e + 1.f);
}

// LLC-direct (agent-coherent) 16B fragment load as 2x8B relaxed atomics.
static __device__ inline bf16x8 ld_frag(const unsigned long long* p){
  union { unsigned long long u[2]; bf16x8 v; } t;
  t.u[0] = __hip_atomic_load((unsigned long long*)p,     __ATOMIC_RELAXED, __HIP_MEMORY_SCOPE_AGENT);
  t.u[1] = __hip_atomic_load((unsigned long long*)p + 1, __ATOMIC_RELAXED, __HIP_MEMORY_SCOPE_AGENT);
  return t.v;
}

// ---------------- sort (stable argsort by descending length) ----------------
__global__ void k_sort(const int* __restrict__ length, int* __restrict__ sorted_idx){
  int b = threadIdx.x;
  if (b >= BB) return;
  int lb = length[b];
  int r = 0;
  for (int o = 0; o < BB; ++o){
    int lo = length[o];
    if (lo > lb || (lo == lb && o < b)) ++r;
  }
  sorted_idx[r] = b;
}

// token / target maps in sorted order
__global__ void k_maps(const int* __restrict__ sorted_idx,
                       const int* __restrict__ inp_seq, const int* __restrict__ tgt_seq,
                       int* __restrict__ tokmap, int* __restrict__ tgtmap){
  int bs = blockIdx.x; int t = threadIdx.x;
  int b = sorted_idx[bs];
  tokmap[bs*SS + t] = inp_seq[b*SS + t];
  tgtmap[bs*SS + t] = tgt_seq[b*SS + t];
}

// hid = z @ l2h_w.T + l2h_b, written DIRECTLY in bf16 fragment-major layout
__global__ __launch_bounds__(256) void k_hid(const float* __restrict__ z,
        const float* __restrict__ w, const float* __restrict__ bias,
        ushort* __restrict__ hb0){
  int id = blockIdx.x*256 + threadIdx.x;      // flat [B,2H] index = b*2048 + c
  int b = id >> 11, c = id & 2047;
  const float4* zr = (const float4*)(z + b*LDM);
  const float4* wr = (const float4*)(w + (size_t)c*LDM);
  float a0=0,a1=0,a2=0,a3=0;
  #pragma unroll 4
  for (int k=0;k<LDM/4;k++){ float4 zz=zr[k], ww=wr[k];
    a0+=zz.x*ww.x; a1+=zz.y*ww.y; a2+=zz.z*ww.z; a3+=zz.w*ww.w; }
  float val = a0+a1+a2+a3 + bias[c];
  int layer = id >> 15, bp = (id >> 10) & 31, j = id & 1023;
  hb0[(layer<<15) + ((j>>3)<<8) + (bp<<3) + (j&7)] = f2bf(val);
}

// ---------------- bf16 MFMA GEMM: C[M,N] = A[M,K] @ Bm[N,K]^T (+bias0+bias1)
// A,B fp32 in HBM, converted to bf16 during LDS staging. 128x128 tile, BK=64.
// optional rowmap gathers A rows. M%128==0, K%64==0; N guarded.
__global__ __launch_bounds__(256) void k_gemm_bf16(
    const float* __restrict__ A, int lda, const int* __restrict__ rowmap,
    const float* __restrict__ Bm,
    const float* __restrict__ bias0, const float* __restrict__ bias1,
    float* __restrict__ C, int M, int N, int K)
{
  __shared__ ushort As[128*72];   // pad 64->72 elems: frag reads 2-way (free)
  __shared__ ushort Bs[128*72];
  const int nt = blockIdx.x * 128, mt = blockIdx.y * 128;
  const int tid = threadIdx.x;
  const int wv = tid >> 6, ln = tid & 63;
  const int wm = wv & 1, wn = wv >> 1;          // 2x2 wave grid (64x64 each)
  const int lc = ln & 15, quad = ln >> 4;
  f32x4 acc[4][4] = {{{0.f,0.f,0.f,0.f}}};

  for (int s = 0; s < K; s += 64){
    __syncthreads();
    #pragma unroll
    for (int cc = 0; cc < 4; ++cc){
      int ch = tid*4 + cc;                 // 0..1023: row=ch>>3, chunk=ch&7
      int r = ch >> 3, c = ch & 7;
      int ar = mt + r;
      const float* ap = A + (size_t)(rowmap ? rowmap[ar] : ar)*lda + s + c*8;
      float4 x = *(const float4*)ap, y = *(const float4*)(ap+4);
      *(bf16x8*)&As[r*72 + c*8] = cvt8(x, y);
      int br = nt + r; if (br >= N) br = N - 1;
      const float* bp = Bm + (size_t)br*K + s + c*8;
      float4 bx = *(const float4*)bp, by = *(const float4*)(bp+4);
      *(bf16x8*)&Bs[r*72 + c*8] = cvt8(bx, by);
    }
    __syncthreads();
    #pragma unroll
    for (int kq = 0; kq < 2; ++kq){
      int cq = kq*4 + quad;
      bf16x8 af[4], bfv[4];
      #pragma unroll
      for (int i=0;i<4;i++) af[i]  = *(const bf16x8*)&As[(wm*64 + i*16 + lc)*72 + cq*8];
      #pragma unroll
      for (int j=0;j<4;j++) bfv[j] = *(const bf16x8*)&Bs[(wn*64 + j*16 + lc)*72 + cq*8];
      #pragma unroll
      for (int i=0;i<4;i++)
        #pragma unroll
        for (int j=0;j<4;j++)
          acc[i][j] = __builtin_amdgcn_mfma_f32_16x16x32_bf16(af[i], bfv[j], acc[i][j], 0, 0, 0);
    }
  }
  #pragma unroll
  for (int j=0;j<4;j++){
    int col = nt + wn*64 + j*16 + lc;
    if (col < N){
      float badd = (bias0 ? bias0[col] : 0.f) + (bias1 ? bias1[col] : 0.f);
      #pragma unroll
      for (int i=0;i<4;i++){
        int row = mt + wm*64 + i*16 + quad*4;
        #pragma unroll
        for (int r=0;r<4;r++)
          C[(size_t)(row+r)*N + col] = acc[i][j][r] + badd;
      }
    }
  }
}

// ---------------- cooperative persistent RNN recurrence ----------------
// 64 wgs; wg owns cols j0..j0+15 of h, Whh slice bf16 in LDS (frag order).
// Cross-wg h exchange via RELAXED+AGENT atomics (LLC-coherent, no L2 wb/inv).
// Step barrier: single monotonic atomicAdd counter, one poller per wg.
__global__ __launch_bounds__(256) void k_rnn_coop(
    float* __restrict__ buf, const float* __restrict__ whh,
    const ushort* __restrict__ hb0, ushort* __restrict__ hbP,
    int* ctr, int layer)
{
  __shared__ ushort whhF[16384];      // [kblk 0..127][col 0..15][8] bf16 — frag order
  __shared__ float red[4*544];        // [wv][row 0..31][17] padded
  const int wg  = blockIdx.x;
  const int tid = threadIdx.x;
  const int j0  = wg * 16;

  for (int c = tid; c < 4096; c += 256){
    int r = c >> 8, cc = (c & 255) * 4;
    float4 w4 = *(const float4*)&whh[(size_t)(j0 + r)*HH + cc];
    uint2 p;
    p.x = (unsigned)f2bf(w4.x) | ((unsigned)f2bf(w4.y) << 16);
    p.y = (unsigned)f2bf(w4.z) | ((unsigned)f2bf(w4.w) << 16);
    *(uint2*)&whhF[((cc >> 3)*16 + r)*8 + (cc & 7)] = p;
  }
  const int lane = tid & 63, wv = tid >> 6;
  const int col = lane & 15, quad = lane >> 4;
  const int ob = tid >> 3, oj = (tid << 1) & 15;
  const ushort* src0 = hb0 + (layer << 15);

  float2 pre = *(const float2*)&buf[((size_t)ob*SS + 0)*HH + j0 + oj];
  __syncthreads();

  for (int t = 0; t < SS; ++t){
    const ushort* src = (t == 0) ? src0 : hbP + (1 - (t & 1)) * 32768;
    ushort* dst = hbP + (t & 1) * 32768;
    const unsigned long long* s64 = (const unsigned long long*)src;

    bf16x8 a0f[8], a1f[8];
    #pragma unroll
    for (int ks = 0; ks < 8; ++ks){
      int kb = wv*32 + ks*4 + quad;
      const unsigned long long* p = s64 + (kb << 6) + (col << 1);
      a0f[ks] = ld_frag(p);
      a1f[ks] = ld_frag(p + 32);
    }
    f32x4 acc0 = {0.f,0.f,0.f,0.f}, acc1 = {0.f,0.f,0.f,0.f};
    #pragma unroll
    for (int ks = 0; ks < 8; ++ks){
      int kb = wv*32 + ks*4 + quad;
      bf16x8 bfr = *(const bf16x8*)&whhF[(kb*16 + col)*8];
      acc0 = __builtin_amdgcn_mfma_f32_16x16x32_bf16(a0f[ks], bfr, acc0, 0, 0, 0);
      acc1 = __builtin_amdgcn_mfma_f32_16x16x32_bf16(a1f[ks], bfr, acc1, 0, 0, 0);
    }
    #pragma unroll
    for (int r = 0; r < 4; ++r){
      red[wv*544 + (quad*4 + r)*17 + col]        = acc0[r];
      red[wv*544 + (16 + quad*4 + r)*17 + col]   = acc1[r];
    }
    __syncthreads();

    int ro = ob*17 + oj;
    float s0 = red[ro]   + red[544 + ro]   + red[1088 + ro]   + red[1632 + ro];
    float s1 = red[ro+1] + red[544 + ro+1] + red[1088 + ro+1] + red[1632 + ro+1];
    float v0 = ftanh(pre.x + s0);
    float v1 = ftanh(pre.y + s1);
    int k = j0 + oj;
    unsigned pk = (unsigned)f2bf(v0) | ((unsigned)f2bf(v1) << 16);
    __hip_atomic_store((unsigned*)dst + ((k >> 3) << 7) + (ob << 2) + ((k & 7) >> 1),
                       pk, __ATOMIC_RELAXED, __HIP_MEMORY_SCOPE_AGENT);

    // all 256 threads' stores durable at LLC, then ONE counter bump per wg
    asm volatile("s_waitcnt vmcnt(0)" ::: "memory");
    __syncthreads();
    if (tid == 0)
      __hip_atomic_fetch_add(ctr, 1, __ATOMIC_RELAXED, __HIP_MEMORY_SCOPE_AGENT);

    // off-protocol (cached): fp32 h for later GEMMs + next pre prefetch
    *(float2*)&buf[((size_t)ob*SS + t)*HH + j0 + oj] = make_float2(v0, v1);
    int tn2 = (t + 1 < SS) ? t + 1 : t;
    pre = *(const float2*)&buf[((size_t)ob*SS + tn2)*HH + j0 + oj];

    if (tid == 0){
      int tv = (t + 1) * NWG;
      while (__hip_atomic_load(ctr, __ATOMIC_RELAXED, __HIP_MEMORY_SCOPE_AGENT) < tv) {}
    }
    __syncthreads();
  }
}

// ---------------- fused cluster logsumexp ----------------
__global__ __launch_bounds__(256) void k_cluster(
    const float* __restrict__ proj, int Kp,
    const float* __restrict__ W, int Nc,
    float* __restrict__ stats, int ci)
{
  __shared__ float ps[4][4][256];
  int lane = threadIdx.x & 63;
  int wvl  = threadIdx.x >> 6;
  int r0 = (blockIdx.x*4 + wvl) * 4;
  for (int r=0;r<4;r++)
    for (int k=lane;k<Kp;k+=64)
      ps[wvl][r][k] = proj[(size_t)(r0+r)*Kp + k];
  __syncthreads();
  float mx[4], sm[4];
  #pragma unroll
  for (int r=0;r<4;r++){ mx[r]=-1e30f; sm[r]=0.f; }
  for (int n=lane; n<Nc; n+=64){
    const float* wr = W + (size_t)n*Kp;
    float l[4]={0.f,0.f,0.f,0.f};
    for (int k=0;k<Kp;k+=4){
      float4 w4 = *(const float4*)(wr+k);
      #pragma unroll
      for (int r=0;r<4;r++){
        l[r] += w4.x*ps[wvl][r][k] + w4.y*ps[wvl][r][k+1]
              + w4.z*ps[wvl][r][k+2] + w4.w*ps[wvl][r][k+3];
      }
    }
    #pragma unroll
    for (int r=0;r<4;r++){
      float nm = fmaxf(mx[r], l[r]);
      sm[r] = sm[r]*__expf(mx[r]-nm) + __expf(l[r]-nm);
      mx[r] = nm;
    }
  }
  #pragma unroll
  for (int r=0;r<4;r++){
    for (int off=32; off; off>>=1){
      float om = __shfl_down(mx[r], off);
      float os = __shfl_down(sm[r], off);
      float nm = fmaxf(mx[r], om);
      sm[r] = sm[r]*__expf(mx[r]-nm) + os*__expf(om-nm);
      mx[r] = nm;
    }
    if (lane==0){
      stats[(size_t)(r0+r)*6 + ci*2 + 0] = mx[r];
      stats[(size_t)(r0+r)*6 + ci*2 + 1] = sm[r];
    }
  }
}

// ---------------- target logit for tail clusters (one wave per row) ----------------
__global__ __launch_bounds__(256) void k_tlogit(
    const int* __restrict__ tgtmap,
    const float* __restrict__ proj0, const float* __restrict__ proj1, const float* __restrict__ proj2,
    const float* __restrict__ w0, const float* __restrict__ w1, const float* __restrict__ w2,
    float* __restrict__ tlogit)
{
  int lane = threadIdx.x & 63;
  int row = (blockIdx.x * 256 + threadIdx.x) >> 6;
  int tgt = tgtmap[row];
  float acc = 0.f;
  const float* pr = nullptr; const float* wr = nullptr; int Kp = 0;
  if      (tgt >= 1000){ pr = proj2 + (size_t)row*16;  wr = w2 + (size_t)(tgt-1000)*16;  Kp=16;  }
  else if (tgt >= 100) { pr = proj1 + (size_t)row*64;  wr = w1 + (size_t)(tgt-100)*64;   Kp=64;  }
  else if (tgt >= 30)  { pr = proj0 + (size_t)row*256; wr = w0 + (size_t)(tgt-30)*256;   Kp=256; }
  for (int k=lane; k<Kp; k+=64) acc += pr[k]*wr[k];
  for (int off=32; off; off>>=1) acc += __shfl_down(acc, off);
  if (lane==0) tlogit[row] = acc;
}

// ---------------- final: head LSE + assemble NLL, reduce ----------------
__global__ __launch_bounds__(256) void k_final(
    const float* __restrict__ head, const float* __restrict__ stats,
    const float* __restrict__ tlogit, const int* __restrict__ tgtmap,
    float* __restrict__ out)
{
  int row = blockIdx.x*256 + threadIdx.x;
  int tgt = tgtmap[row];
  float nll = 0.f;
  if (tgt != 0){
    const float* hrow = head + (size_t)row*33;
    float m = hrow[0];
    #pragma unroll
    for (int i=1;i<33;i++) m = fmaxf(m, hrow[i]);
    float s = 0.f;
    #pragma unroll
    for (int i=0;i<33;i++) s += __expf(hrow[i]-m);
    float lse = __logf(s) + m;
    int ci = (tgt>=1000) ? 2 : (tgt>=100) ? 1 : (tgt>=30) ? 0 : -1;
    if (ci < 0){
      nll = lse - hrow[tgt];
    } else {
      float cm = stats[(size_t)row*6 + ci*2 + 0];
      float cs = stats[(size_t)row*6 + ci*2 + 1];
      nll = lse - hrow[30+ci] + (__logf(cs) + cm - tlogit[row]);
    }
  }
  float v = nll;
  for (int off=32; off; off>>=1) v += __shfl_down(v, off);
  __shared__ float wsum[4];
  int lane = threadIdx.x & 63, wv = threadIdx.x >> 6;
  if (lane==0) wsum[wv] = v;
  __syncthreads();
  if (threadIdx.x==0) atomicAdd(out, wsum[0]+wsum[1]+wsum[2]+wsum[3]);
}

extern "C" void kernel_launch(void* const* d_in, const int* in_sizes, int n_in,
                              void* d_out, int out_size, void* d_ws, size_t ws_size,
                              hipStream_t stream)
{
  const float* z      = (const float*)d_in[0];
  const float* emb    = (const float*)d_in[1];
  const float* l2h_w  = (const float*)d_in[2];
  const float* l2h_b  = (const float*)d_in[3];
  const float* w0ih   = (const float*)d_in[4];
  const float* w0hh   = (const float*)d_in[5];
  const float* b0ih   = (const float*)d_in[6];
  const float* b0hh   = (const float*)d_in[7];
  const float* w1ih   = (const float*)d_in[8];
  const float* w1hh   = (const float*)d_in[9];
  const float* b1ih   = (const float*)d_in[10];
  const float* b1hh   = (const float*)d_in[11];
  const float* head_w = (const float*)d_in[12];
  const float* p0     = (const float*)d_in[13];
  const float* tw0    = (const float*)d_in[14];
  const float* p1     = (const float*)d_in[15];
  const float* tw1    = (const float*)d_in[16];
  const float* p2     = (const float*)d_in[17];
  const float* tw2    = (const float*)d_in[18];
  const int* inp_seq  = (const int*)d_in[19];
  const int* tgt_seq  = (const int*)d_in[20];
  const int* length   = (const int*)d_in[21];

  float* ws   = (float*)d_ws;
  ushort* hb0 = (ushort*)ws;                      // 65536 ushorts
  ushort* hbP = hb0 + 65536;                      // 65536 ushorts
  float* bufA = ws + 65536;                       // 8192*1024  (pre0 -> h1; later head/proj/stats)
  float* bufB = bufA + (size_t)NROW*HH;           // 8192*1024  (pre1 -> h2)
  int*   ibuf = (int*)(bufB + (size_t)NROW*HH);
  int* sorted_idx = ibuf;                         // 32
  int* tokmap = ibuf + 32;                        // 8192
  int* tgtmap = tokmap + NROW;                    // 8192
  int* flags  = tgtmap + NROW;                    // 128 (layer counters at [0],[1])
  float* headL = bufA;                            // 8192*33
  float* proj0 = headL + (size_t)NROW*33;         // 8192*256
  float* proj1 = proj0 + (size_t)NROW*256;        // 8192*64
  float* proj2 = proj1 + (size_t)NROW*64;         // 8192*16
  float* stats = proj2 + (size_t)NROW*16;         // 8192*6
  float* tlog  = stats + (size_t)NROW*6;          // 8192

  float* outF = (float*)d_out;
  hipMemsetAsync(outF, 0, sizeof(float), stream);
  hipMemsetAsync(flags, 0, 128*sizeof(int), stream);

  k_sort<<<1, 32, 0, stream>>>(length, sorted_idx);
  k_maps<<<32, 256, 0, stream>>>(sorted_idx, inp_seq, tgt_seq, tokmap, tgtmap);
  k_hid<<<256, 256, 0, stream>>>(z, l2h_w, l2h_b, hb0);

  // pre0 = emb[tok] @ w0ih^T + b0ih + b0hh   (bf16 MFMA, A gathered)
  k_gemm_bf16<<<dim3(HH/128, NROW/128), 256, 0, stream>>>(emb, EE, tokmap, w0ih,
                                                          b0ih, b0hh, bufA, NROW, HH, EE);
  k_rnn_coop<<<NWG, 256, 0, stream>>>(bufA, w0hh, hb0, hbP, flags, 0);      // bufA := h1
  // pre1 = h1 @ w1ih^T + b1ih + b1hh
  k_gemm_bf16<<<dim3(HH/128, NROW/128), 256, 0, stream>>>(bufA, HH, nullptr, w1ih,
                                                          b1ih, b1hh, bufB, NROW, HH, HH);
  k_rnn_coop<<<NWG, 256, 0, stream>>>(bufB, w1hh, hb0, hbP, flags + 1, 1);  // bufB := h2

  // head logits + tail projections (A = h2 fp32)
  k_gemm_bf16<<<dim3(1, NROW/128), 256, 0, stream>>>(bufB, HH, nullptr, head_w,
                                                     nullptr, nullptr, headL, NROW, 33, HH);
  k_gemm_bf16<<<dim3(2, NROW/128), 256, 0, stream>>>(bufB, HH, nullptr, p0,
                                                     nullptr, nullptr, proj0, NROW, 256, HH);
  k_gemm_bf16<<<dim3(1, NROW/128), 256, 0, stream>>>(bufB, HH, nullptr, p1,
                                                     nullptr, nullptr, proj1, NROW, 64, HH);
  k_gemm_bf16<<<dim3(1, NROW/128), 256, 0, stream>>>(bufB, HH, nullptr, p2,
                                                     nullptr, nullptr, proj2, NROW, 16, HH);

  k_cluster<<<NROW/16, 256, 0, stream>>>(proj0, 256, tw0, 70,    stats, 0);
  k_cluster<<<NROW/16, 256, 0, stream>>>(proj1, 64,  tw1, 900,   stats, 1);
  k_cluster<<<NROW/16, 256, 0, stream>>>(proj2, 16,  tw2, 19000, stats, 2);
  k_tlogit<<<NROW/4, 256, 0, stream>>>(tgtmap, proj0, proj1, proj2, tw0, tw1, tw2, tlog);
  k_final<<<NROW/256, 256, 0, stream>>>(headL, stats, tlog, tgtmap, outF);
}